// Round 8
// baseline (73.877 us; speedup 1.0000x reference)
//
#include <hip/hip_runtime.h>

#define NL 17
#define IGN (-100)
#define HD 384
#define NSEQ 1024
#define NT 65536
#define BIGI NT
#define TPB 256          // threads per block
#define TOK 128          // tokens per block
#define NBLK (NT / TOK)  // 512
#define NCHUNK 12        // 384 / 32 cols
#define WPAD 392         // padded bf16 row stride for W (bank spread)

typedef unsigned int u32;
typedef unsigned short u16;
typedef __attribute__((ext_vector_type(8))) short bf16x8;
typedef __attribute__((ext_vector_type(16))) float f32x16;

#define GLOAD_LDS16(g, l) __builtin_amdgcn_global_load_lds(                    \
    (const __attribute__((address_space(1))) u32*)(g),                         \
    (__attribute__((address_space(3))) u32*)(l), 16, 0, 0)

__device__ __forceinline__ u32 cvtpk(float lo, float hi) {
  u32 u;
  asm("v_cvt_pk_bf16_f32 %0, %1, %2" : "=v"(u) : "v"(lo), "v"(hi));
  return u;
}

struct WS {
  u32  cnt;            // ticket counter (memset to 0 each launch)
  u32  pad0[15];
  float ce_part[NBLK];
  float ctx_part[NBLK];
  int   ce_cnt[NBLK];
  int   ctx_cnt[NBLK];
  int   blk_a[NBLK][16];
  int   blk_p[NBLK][16];
  int   blk_c[NBLK][16];
  int   blk_d[NBLK];
};

// ======== fused: stream+MFMA+scan per 128-token block; last block finalizes ========
__global__ __launch_bounds__(256, 2) void k_main(const float* __restrict__ emb,
                                                 const float* __restrict__ cw,
                                                 const float* __restrict__ cb,
                                                 const int* __restrict__ labels,
                                                 const int* __restrict__ mask,
                                                 WS* __restrict__ ws,
                                                 float* __restrict__ out) {
  __shared__ float4 tile[4][TOK * 8];   // 4 x 16 KB quad buffer (gload_lds dest)
  __shared__ u16    sWh[NL * WPAD];     // 13.3 KB W in bf16
  __shared__ float  sce[2], sctx[2];
  __shared__ int    svc[2], spc[2];
  __shared__ float  sbctx;
  __shared__ int    sbcnt;
  __shared__ int    sla[16], slp[16], slc[16], sld, slast;

  const int tid = threadIdx.x, lane = tid & 63, wid = tid >> 6;
  const int b = blockIdx.x;
  const int token = b * TOK + tid;      // valid token only for tid < TOK

  // ---- W -> LDS as bf16 (once) ----
  for (int i = tid; i < NL * (HD / 2); i += TPB) {   // 17*192 bf16-pairs
    int c = i / (HD / 2), p = i % (HD / 2);
    u32 pk = cvtpk(cw[c * HD + 2 * p], cw[c * HD + 2 * p + 1]);
    *(u32*)&sWh[c * WPAD + 2 * p] = pk;
  }
  if (tid < 16) { sla[tid] = BIGI; slp[tid] = BIGI; slc[tid] = 0; }
  if (tid == 16) sld = BIGI;
  __syncthreads();   // drains W's global loads -> vmcnt counting below is exact

  // ---- staging geometry: 128 rows x 8 f4 per chunk; 256 threads x 4 loads ----
  // slot s = k*256 + tid, row = k*32 + (tid>>3), holds col c4 ^ (rb&7)
  const int rb  = tid >> 3;             // 0..31
  const int c4  = tid & 7;
  const int gc4 = c4 ^ (rb & 7);        // pre-swizzled source column
  const float* src0 = emb + (size_t)b * TOK * HD + (size_t)rb * HD + gc4 * 4;
  const int wbase = __builtin_amdgcn_readfirstlane(wid * 64);

  // issue chunks 0,1 (8 outstanding per wave)
#pragma unroll
  for (int k = 0; k < 4; ++k)
    GLOAD_LDS16(src0 + (size_t)k * 32 * HD, &tile[0][k * 256 + wbase]);
#pragma unroll
  for (int k = 0; k < 4; ++k)
    GLOAD_LDS16(src0 + 32 + (size_t)k * 32 * HD, &tile[1][k * 256 + wbase]);

  // ---- MFMA geometry: each wave owns one 32-token tile ----
  const int cls = lane & 31;
  const int kh  = lane >> 5;
  const int clsS = (cls < NL) ? cls : 0;
  const int row0 = wid * 32 + (lane & 31);
  // ctx: thread handles half a row: r = tid&127, cols [h*16, h*16+16)
  const int cr0 = tid & 127;
  const int cr1 = (cr0 < TOK - 1) ? cr0 + 1 : cr0;
  const int chf = tid >> 7;             // 0: q 0..3, 1: q 4..7
  const int cx0 = cr0 & 7, cx1 = cr1 & 7;

  f32x16 d0 = {0.f};
  float ctxacc = 0.f;

  auto bfrag = [&](const float4* tb, int s) -> bf16x8 {
    int g0 = (s * 4 + kh * 2) ^ (row0 & 7);
    int g1 = (s * 4 + kh * 2 + 1) ^ (row0 & 7);
    float4 f0 = tb[(row0 << 3) | g0];
    float4 f1 = tb[(row0 << 3) | g1];
    union { u32 u[4]; bf16x8 v; } X;
    X.u[0] = cvtpk(f0.x, f0.y); X.u[1] = cvtpk(f0.z, f0.w);
    X.u[2] = cvtpk(f1.x, f1.y); X.u[3] = cvtpk(f1.z, f1.w);
    return X.v;
  };
  auto afrag = [&](int ch, int s) -> bf16x8 {
    if (cls < NL)
      return *(const bf16x8*)&sWh[clsS * WPAD + ch * 32 + s * 16 + kh * 8];
    union { u32 u[4]; bf16x8 v; } X;
    X.u[0] = 0; X.u[1] = 0; X.u[2] = 0; X.u[3] = 0;
    return X.v;
  };

  auto compute = [&](int ch, const float4* tb) {
#pragma unroll
    for (int qq = 0; qq < 4; ++qq) {
      int q = chf * 4 + qq;
      float4 a  = tb[(cr0 << 3) | (q ^ cx0)];
      float4 nb = tb[(cr1 << 3) | (q ^ cx1)];
      float e0 = a.x - nb.x, e1 = a.y - nb.y, e2 = a.z - nb.z, e3 = a.w - nb.w;
      ctxacc = fmaf(e0, e0, fmaf(e1, e1, fmaf(e2, e2, fmaf(e3, e3, ctxacc))));
    }
    bf16x8 a0 = afrag(ch, 0), a1 = afrag(ch, 1);
    bf16x8 b0 = bfrag(tb, 0), b1 = bfrag(tb, 1);
    d0 = __builtin_amdgcn_mfma_f32_32x32x16_bf16(a0, b0, d0, 0, 0, 0);
    d0 = __builtin_amdgcn_mfma_f32_32x32x16_bf16(a1, b1, d0, 0, 0, 0);
  };

  // main loop: 2-deep prefetch, quad buffer, one barrier per chunk
#pragma unroll 1
  for (int ch = 0; ch < NCHUNK - 2; ++ch) {
    const float* srcn = src0 + (size_t)(ch + 2) * 32;
    float4* dstb = tile[(ch + 2) & 3];
#pragma unroll
    for (int k = 0; k < 4; ++k)
      GLOAD_LDS16(srcn + (size_t)k * 32 * HD, &dstb[k * 256 + wbase]);
    asm volatile("s_waitcnt vmcnt(8)" ::: "memory");   // chunk ch's 4 complete
    __builtin_amdgcn_sched_barrier(0);
    __builtin_amdgcn_s_barrier();
    __builtin_amdgcn_sched_barrier(0);
    compute(ch, tile[ch & 3]);
  }
  asm volatile("s_waitcnt vmcnt(4)" ::: "memory");
  __builtin_amdgcn_sched_barrier(0);
  __builtin_amdgcn_s_barrier();
  __builtin_amdgcn_sched_barrier(0);
  compute(NCHUNK - 2, tile[(NCHUNK - 2) & 3]);
  asm volatile("s_waitcnt vmcnt(0)" ::: "memory");
  __builtin_amdgcn_sched_barrier(0);
  __builtin_amdgcn_s_barrier();
  __builtin_amdgcn_sched_barrier(0);
  compute(NCHUNK - 1, tile[(NCHUNK - 1) & 3]);
  __syncthreads();

  // ---- spill logits [128][21] into tile[0]; ctx halves into tile[1] ----
  float* logit = (float*)&tile[0][0];
  float* pcxp  = (float*)&tile[1][0];
#pragma unroll
  for (int r = 0; r < 16; ++r) {
    int row = (r & 3) + 8 * (r >> 2) + 4 * kh;       // class
    if (row < NL) logit[(wid * 32 + (lane & 31)) * 21 + row] = d0[r];
  }
  pcxp[tid] = ctxacc;
  __syncthreads();

  // ---- label scan ----
  int lb = IGN, mk = 0;
  if (tid < TOK) { lb = labels[token]; mk = mask[token]; }
  int lbm = (mk > 0) ? lb : IGN;
  if (lbm == 0) atomicMin(&sld, token);
  else if (lbm >= 1) { atomicMin(&sla[lbm - 1], token); atomicAdd(&slc[lbm - 1], 1); }
  __syncthreads();
  if (lbm >= 1 && token > sla[lbm - 1]) atomicMin(&slp[lbm - 1], token);

  // ---- softmax + CE + ctx pair (tid < 128) ----
  float cev = 0.f, ctxv = 0.f;
  bool valid = false, pair = false;
  if (tid < TOK) {
    float lg[NL];
#pragma unroll
    for (int c = 0; c < NL; ++c) lg[c] = logit[tid * 21 + c] + cb[c];
    float m = lg[0];
#pragma unroll
    for (int c = 1; c < NL; ++c) m = fmaxf(m, lg[c]);
    float s = 0.f;
#pragma unroll
    for (int c = 0; c < NL; ++c) s += __expf(lg[c] - m);
    float lse = m + __logf(s);
    int safe = (lb == IGN) ? 0 : lb;
    float ll = 0.f;
#pragma unroll
    for (int c = 0; c < NL; ++c) ll = (c == safe) ? lg[c] : ll;
    valid = (lb != IGN);
    cev = valid ? (lse - ll) : 0.f;
    int nlb = (tid < TOK - 1) ? labels[token + 1] : IGN;
    pair = (tid < TOK - 1) && valid && (lb == nlb) && (lb > 0);
    float cs = pcxp[tid] + pcxp[tid + 128];
    ctxv = pair ? cs * (1.0f / HD) : 0.f;
  }
  unsigned long long bv = __ballot(valid);
  unsigned long long bp = __ballot(pair);
#pragma unroll
  for (int off = 32; off; off >>= 1) {
    cev  += __shfl_xor(cev, off, 64);
    ctxv += __shfl_xor(ctxv, off, 64);
  }
  if (lane == 0 && wid < 2) { sce[wid] = cev; sctx[wid] = ctxv; svc[wid] = __popcll(bv); spc[wid] = __popcll(bp); }

  if (wid == 2) {   // cross-block boundary pair (b*128+127, b*128+128)
    int t = b * TOK + TOK - 1;
    float bc = 0.f; int bn = 0;
    if (((t + 1) & (NSEQ - 1)) != 0) {
      int l0 = labels[t], l1 = labels[t + 1];
      if (l0 != IGN && l0 == l1 && l0 > 0) {
        const float* ra = emb + (size_t)t * HD;
        const float* rbp = ra + HD;
        float a = 0.f;
#pragma unroll
        for (int j = 0; j < 6; ++j) {
          float dd = ra[lane + 64 * j] - rbp[lane + 64 * j];
          a = fmaf(dd, dd, a);
        }
#pragma unroll
        for (int off = 32; off; off >>= 1) a += __shfl_xor(a, off, 64);
        bc = a * (1.0f / HD); bn = 1;
      }
    }
    if (lane == 0) { sbctx = bc; sbcnt = bn; }
  }
  __syncthreads();
  if (tid < 16) {
    ws->blk_a[b][tid] = sla[tid];
    ws->blk_p[b][tid] = slp[tid];
    ws->blk_c[b][tid] = slc[tid];
  }
  if (tid == 16) ws->blk_d[b] = sld;
  if (tid == 0) {
    ws->ce_part[b]  = sce[0] + sce[1];
    ws->ce_cnt[b]   = svc[0] + svc[1];
    ws->ctx_part[b] = sctx[0] + sctx[1] + sbctx;
    ws->ctx_cnt[b]  = spc[0] + spc[1] + sbcnt;
  }

  // ---- last-block finalize (device-scope ticket) ----
  __threadfence();
  __syncthreads();
  if (tid == 0) {
    u32 v = atomicAdd(&ws->cnt, 1u);
    slast = (v == (u32)(NBLK - 1));
  }
  __syncthreads();
  if (!slast) return;
  __threadfence();   // acquire: all blocks' ws writes visible

  char* scr = (char*)&tile[0][0];
  double* Rce  = (double*)scr;
  double* Rctx = (double*)(scr + 2048);
  int* Rvc = (int*)(scr + 4096);
  int* Rpc = (int*)(scr + 5120);
  int* Rd  = (int*)(scr + 6144);
  int* M1  = (int*)(scr + 7168);
  int* M2  = (int*)(scr + 8192);
  int* CN  = (int*)(scr + 9216);
  int* Ga  = (int*)(scr + 10240);
  int* Gp  = (int*)(scr + 10304);
  int* Gc  = (int*)(scr + 10368);
  float* Qs = (float*)(scr + 10432);
  int* Qc  = (int*)(scr + 10448);

  {
    double sc = 0, sx = 0; int cv = 0, cp = 0, md = BIGI;
#pragma unroll
    for (int k = 0; k < 2; ++k) {
      int i = tid * 2 + k;
      sc += ws->ce_part[i]; sx += ws->ctx_part[i];
      cv += ws->ce_cnt[i];  cp += ws->ctx_cnt[i];
      md = min(md, ws->blk_d[i]);
    }
    Rce[tid] = sc; Rctx[tid] = sx; Rvc[tid] = cv; Rpc[tid] = cp; Rd[tid] = md;
  }
  {
    const int type = tid & 15, seg = tid >> 4;   // 16 segs x 32 blocks
    int m1 = BIGI, m2 = BIGI, cnt = 0;
    for (int k = 0; k < 32; ++k) {
      int bb = seg * 32 + k;
      int x = ws->blk_a[bb][type];
      if (x < m1) { m2 = m1; m1 = x; } else if (x < m2) { m2 = x; }
      int y = ws->blk_p[bb][type];
      if (y < m1) { m2 = m1; m1 = y; } else if (y < m2) { m2 = y; }
      cnt += ws->blk_c[bb][type];
    }
    M1[tid] = m1; M2[tid] = m2; CN[tid] = cnt;
  }
  __syncthreads();
  for (int s = 128; s > 0; s >>= 1) {
    if (tid < s) {
      Rce[tid] += Rce[tid + s]; Rctx[tid] += Rctx[tid + s];
      Rvc[tid] += Rvc[tid + s]; Rpc[tid] += Rpc[tid + s];
      Rd[tid] = min(Rd[tid], Rd[tid + s]);
    }
    __syncthreads();
  }
  if (tid < 16) {
    int m1 = BIGI, m2 = BIGI, cnt = 0;
    for (int seg = 0; seg < 16; ++seg) {
      int a1 = M1[seg * 16 + tid], a2 = M2[seg * 16 + tid];
      int n1 = min(m1, a1);
      int n2 = min(max(m1, a1), min(m2, a2));
      m1 = n1; m2 = n2;
      cnt += CN[seg * 16 + tid];
    }
    Ga[tid] = m1; Gp[tid] = m2; Gc[tid] = cnt;
  }
  __syncthreads();

  const int gd = Rd[0];
  float qsum = 0.f; int qcnt = 0;
  for (int tt = 0; tt < 4; ++tt) {
    int t = wid * 4 + tt;
    int a = Ga[t], p = Gp[t], c = Gc[t];
    int nmin = BIGI;
#pragma unroll
    for (int u = 0; u < 16; ++u) if (u != t) nmin = min(nmin, Ga[u]);
    bool ok = (c >= 2) && (nmin < BIGI) && (gd < BIGI);
    if (ok) {
      const float* A  = emb + (size_t)min(a, NT - 1) * HD;
      const float* P  = emb + (size_t)min(p, NT - 1) * HD;
      const float* Ng = emb + (size_t)min(nmin, NT - 1) * HD;
      const float* D  = emb + (size_t)min(gd, NT - 1) * HD;
      float sap = 0.f, san = 0.f, sad = 0.f;
#pragma unroll
      for (int j = 0; j < 6; ++j) {
        int idx = lane + 64 * j;
        float av = A[idx];
        float d1 = av - P[idx] + 1e-6f;  sap = fmaf(d1, d1, sap);
        float d2 = av - Ng[idx] + 1e-6f; san = fmaf(d2, d2, san);
        float d3 = av - D[idx] + 1e-6f;  sad = fmaf(d3, d3, sad);
      }
#pragma unroll
      for (int off = 32; off; off >>= 1) {
        sap += __shfl_xor(sap, off, 64);
        san += __shfl_xor(san, off, 64);
        sad += __shfl_xor(sad, off, 64);
      }
      float pd = sqrtf(sap), nd = sqrtf(san), dd = sqrtf(sad);
      qsum += fmaxf(pd - nd + 1.0f, 0.f) + fmaxf(pd - dd + 2.0f, 0.f);
      qcnt += 1;
    }
  }
  if (lane == 0) { Qs[wid] = qsum; Qc[wid] = qcnt; }
  __syncthreads();
  if (tid == 0) {
    double tq = (double)Qs[0] + Qs[1] + Qs[2] + Qs[3];
    int tqc = Qc[0] + Qc[1] + Qc[2] + Qc[3];
    double ce   = Rce[0] / (double)max(Rvc[0], 1);
    double ctx  = (Rpc[0] > 0) ? Rctx[0] / (double)Rpc[0] : 0.0;
    double quad = (tqc > 0) ? tq / (double)tqc : 0.0;
    out[0] = (float)(ce + 0.5 * quad + 0.1 * ctx);
  }
}

extern "C" void kernel_launch(void* const* d_in, const int* in_sizes, int n_in,
                              void* d_out, int out_size, void* d_ws, size_t ws_size,
                              hipStream_t stream) {
  const float* emb    = (const float*)d_in[0];
  const float* cw     = (const float*)d_in[1];
  const float* cb     = (const float*)d_in[2];
  const int*   labels = (const int*)d_in[3];
  const int*   mask   = (const int*)d_in[4];
  WS* ws = (WS*)d_ws;
  float* out = (float*)d_out;

  hipMemsetAsync(d_ws, 0, 4, stream);   // zero the ticket counter (graph-capturable)
  k_main<<<NBLK, TPB, 0, stream>>>(emb, cw, cb, labels, mask, ws, out);
}

// Round 9
// 39.461 us; speedup vs baseline: 1.8721x; 1.8721x over previous
//
#include <hip/hip_runtime.h>

#define NL 17
#define IGN (-100)
#define HD 384
#define NSEQ 1024
#define NT 65536
#define BIGI NT
#define TPB 256
#define NBLK (NT / TPB)        // 256
#define NCHUNK 12              // 384 / 32 cols
#define CF4 8                  // float4 per row per chunk
#define WPAD 392               // u16 row stride for bf16 W (16B-aligned, bank-spread)

typedef unsigned int u32;
typedef unsigned short u16;
typedef __attribute__((ext_vector_type(8))) short bf16x8;
typedef __attribute__((ext_vector_type(16))) float f32x16;

#define GLOAD_LDS16(g, l) __builtin_amdgcn_global_load_lds(                    \
    (const __attribute__((address_space(1))) u32*)(g),                         \
    (__attribute__((address_space(3))) u32*)(l), 16, 0, 0)

__device__ __forceinline__ u32 cvtpk(float lo, float hi) {
  u32 u;
  asm("v_cvt_pk_bf16_f32 %0, %1, %2" : "=v"(u) : "v"(lo), "v"(hi));
  return u;
}

struct WS {
  float ce_part[NBLK];
  float ctx_part[NBLK];
  int   ce_cnt[NBLK];
  int   ctx_cnt[NBLK];
  int   blk_a[NBLK][16];
  int   blk_p[NBLK][16];
  int   blk_c[NBLK][16];
  int   blk_d[NBLK];
};

// ---------------- main: depth-3 gload_lds + MFMA + fused label scan ----------------
__global__ __launch_bounds__(256, 1) void k_main(const float* __restrict__ emb,
                                                 const float* __restrict__ cw,
                                                 const float* __restrict__ cb,
                                                 const int* __restrict__ labels,
                                                 const int* __restrict__ mask,
                                                 WS* __restrict__ ws) {
  __shared__ float4 tile[4][TPB * CF4];   // 4 x 32 KB quad buffer (gload_lds dest)
  __shared__ u16    sWh[NL * WPAD];       // 13.3 KB W in bf16
  __shared__ float  pcx0[4][64], pcx1[4][64];   // per-(row,kh) ctx partials
  __shared__ float  sce[4], sctx[4];
  __shared__ int    svc[4], spc[4];
  __shared__ float  sbctx;
  __shared__ int    sbcnt;
  __shared__ int    sla[16], slp[16], slc[16], sld;

  const int tid = threadIdx.x, lane = tid & 63, wid = tid >> 6;
  const int b = blockIdx.x;
  const int token = b * TPB + tid;

  // ---- W -> LDS as bf16 (once); scan-LDS init ----
  for (int i = tid; i < NL * (HD / 2); i += TPB) {
    int c = i / (HD / 2), p = i % (HD / 2);
    u32 pk = cvtpk(cw[c * HD + 2 * p], cw[c * HD + 2 * p + 1]);
    *(u32*)&sWh[c * WPAD + 2 * p] = pk;
  }
  if (tid < 16) { sla[tid] = BIGI; slp[tid] = BIGI; slc[tid] = 0; }
  if (tid == 16) sld = BIGI;
  __syncthreads();   // drains W's global loads -> vmcnt counting below is exact

  // ---- staging geometry (round-5..7 proven) ----
  const int rb  = tid >> 3;
  const int c4  = tid & 7;
  const int gc4 = c4 ^ (rb & 7);          // pre-swizzled source column
  const float* src0 = emb + (size_t)b * TPB * HD + (size_t)rb * HD + gc4 * 4;
  const int wbase = __builtin_amdgcn_readfirstlane(wid * 64);

  auto issue = [&](int c) {
    const float* s = src0 + (size_t)c * 32;
    float4* d = tile[c & 3];
#pragma unroll
    for (int k = 0; k < CF4; ++k)
      GLOAD_LDS16(s + (size_t)k * 32 * HD, &d[k * 256 + wbase]);
  };

  // prologue: 3 chunks in flight
  issue(0); issue(1); issue(2);

  // ---- MFMA geometry ----
  const int cls = lane & 31;
  const int kh  = lane >> 5;
  const int clsS = (cls < NL) ? cls : 0;
  const int row0 = wid * 64 + (lane & 31);
  const int row1 = row0 + 32;
  const int row0n = row0 + 1;                          // always in tile
  const int row1n = (row1 < TPB - 1) ? row1 + 1 : row1; // clamp 255

  f32x16 d0 = {0.f}, d1 = {0.f};
  float acc0 = 0.f, acc1 = 0.f;

  auto afrag = [&](int ch, int s) -> bf16x8 {
    if (cls < NL)
      return *(const bf16x8*)&sWh[clsS * WPAD + ch * 32 + s * 16 + kh * 8];
    union { u32 u[4]; bf16x8 v; } Z;
    Z.u[0] = 0; Z.u[1] = 0; Z.u[2] = 0; Z.u[3] = 0;
    return Z.v;
  };

  auto compute = [&](int ch, const float4* tb) {
    float4 t0[4], t1[4], n0[4], n1[4];
#pragma unroll
    for (int j = 0; j < 4; ++j) {
      int q = (j >> 1) * 4 + kh * 2 + (j & 1);
      t0[j] = tb[(row0  << 3) | (q ^ (row0  & 7))];
      t1[j] = tb[(row1  << 3) | (q ^ (row1  & 7))];
      n0[j] = tb[(row0n << 3) | (q ^ (row0n & 7))];
      n1[j] = tb[(row1n << 3) | (q ^ (row1n & 7))];
    }
    // ctx partials from the same registers (fp32)
#pragma unroll
    for (int j = 0; j < 4; ++j) {
      float a0x = t0[j].x - n0[j].x, a0y = t0[j].y - n0[j].y;
      float a0z = t0[j].z - n0[j].z, a0w = t0[j].w - n0[j].w;
      acc0 = fmaf(a0x, a0x, fmaf(a0y, a0y, fmaf(a0z, a0z, fmaf(a0w, a0w, acc0))));
      float a1x = t1[j].x - n1[j].x, a1y = t1[j].y - n1[j].y;
      float a1z = t1[j].z - n1[j].z, a1w = t1[j].w - n1[j].w;
      acc1 = fmaf(a1x, a1x, fmaf(a1y, a1y, fmaf(a1z, a1z, fmaf(a1w, a1w, acc1))));
    }
    // B fragments (identical construction to rounds 6-8)
    union { u32 u[4]; bf16x8 v; } B00, B01, B10, B11;
    B00.u[0] = cvtpk(t0[0].x, t0[0].y); B00.u[1] = cvtpk(t0[0].z, t0[0].w);
    B00.u[2] = cvtpk(t0[1].x, t0[1].y); B00.u[3] = cvtpk(t0[1].z, t0[1].w);
    B01.u[0] = cvtpk(t0[2].x, t0[2].y); B01.u[1] = cvtpk(t0[2].z, t0[2].w);
    B01.u[2] = cvtpk(t0[3].x, t0[3].y); B01.u[3] = cvtpk(t0[3].z, t0[3].w);
    B10.u[0] = cvtpk(t1[0].x, t1[0].y); B10.u[1] = cvtpk(t1[0].z, t1[0].w);
    B10.u[2] = cvtpk(t1[1].x, t1[1].y); B10.u[3] = cvtpk(t1[1].z, t1[1].w);
    B11.u[0] = cvtpk(t1[2].x, t1[2].y); B11.u[1] = cvtpk(t1[2].z, t1[2].w);
    B11.u[2] = cvtpk(t1[3].x, t1[3].y); B11.u[3] = cvtpk(t1[3].z, t1[3].w);
    bf16x8 a0 = afrag(ch, 0), a1 = afrag(ch, 1);
    d0 = __builtin_amdgcn_mfma_f32_32x32x16_bf16(a0, B00.v, d0, 0, 0, 0);
    d0 = __builtin_amdgcn_mfma_f32_32x32x16_bf16(a1, B01.v, d0, 0, 0, 0);
    d1 = __builtin_amdgcn_mfma_f32_32x32x16_bf16(a0, B10.v, d1, 0, 0, 0);
    d1 = __builtin_amdgcn_mfma_f32_32x32x16_bf16(a1, B11.v, d1, 0, 0, 0);
  };

  // main loop: vmcnt(16) drains chunk ch; issue ch+3 AFTER barrier (buffer-safe)
#pragma unroll 1
  for (int ch = 0; ch <= NCHUNK - 4; ++ch) {
    asm volatile("s_waitcnt vmcnt(16)" ::: "memory");
    __builtin_amdgcn_sched_barrier(0);
    __builtin_amdgcn_s_barrier();
    __builtin_amdgcn_sched_barrier(0);
    issue(ch + 3);
    compute(ch, tile[ch & 3]);
  }
  asm volatile("s_waitcnt vmcnt(16)" ::: "memory");
  __builtin_amdgcn_sched_barrier(0);
  __builtin_amdgcn_s_barrier();
  __builtin_amdgcn_sched_barrier(0);
  compute(NCHUNK - 3, tile[(NCHUNK - 3) & 3]);
  asm volatile("s_waitcnt vmcnt(8)" ::: "memory");
  __builtin_amdgcn_sched_barrier(0);
  __builtin_amdgcn_s_barrier();
  __builtin_amdgcn_sched_barrier(0);
  compute(NCHUNK - 2, tile[(NCHUNK - 2) & 3]);
  asm volatile("s_waitcnt vmcnt(0)" ::: "memory");
  __builtin_amdgcn_sched_barrier(0);
  __builtin_amdgcn_s_barrier();
  __builtin_amdgcn_sched_barrier(0);
  compute(NCHUNK - 1, tile[(NCHUNK - 1) & 3]);

  // ---- spill ctx partials + logits ----
  pcx0[wid][lane] = acc0;
  pcx1[wid][lane] = acc1;
  __syncthreads();   // all tile reads done; tile[0] becomes logits

  float* logit = (float*)&tile[0][0];   // 256*21*4 = 21.5 KB < 32 KB
#pragma unroll
  for (int r = 0; r < 16; ++r) {
    int row = (r & 3) + 8 * (r >> 2) + 4 * kh;   // class
    if (row < NL) {
      logit[(wid * 64 + (lane & 31)) * 21 + row] = d0[r];
      logit[(wid * 64 + 32 + (lane & 31)) * 21 + row] = d1[r];
    }
  }
  __syncthreads();

  // ---- fused label scan ----
  int lb = labels[token];
  int mk = mask[token];
  int lbm = (mk > 0) ? lb : IGN;
  if (lbm == 0) atomicMin(&sld, token);
  else if (lbm >= 1 && lbm < NL) { atomicMin(&sla[lbm - 1], token); atomicAdd(&slc[lbm - 1], 1); }
  __syncthreads();
  if (lbm >= 1 && lbm < NL && token > sla[lbm - 1]) atomicMin(&slp[lbm - 1], token);

  // ---- softmax + CE + ctx pair ----
  float lg[NL];
#pragma unroll
  for (int c = 0; c < NL; ++c) lg[c] = logit[tid * 21 + c] + cb[c];
  float m = lg[0];
#pragma unroll
  for (int c = 1; c < NL; ++c) m = fmaxf(m, lg[c]);
  float s = 0.f;
#pragma unroll
  for (int c = 0; c < NL; ++c) s += __expf(lg[c] - m);
  float lse = m + __logf(s);
  int safe = (lb == IGN) ? 0 : lb;
  float ll = 0.f;
#pragma unroll
  for (int c = 0; c < NL; ++c) ll = (c == safe) ? lg[c] : ll;
  bool valid = (lb != IGN);
  float cev = valid ? (lse - ll) : 0.f;

  // gather this row's ctx SSD: partials live at lanes (j, j+32) of this wave
  float cs = (lane < 32) ? (pcx0[wid][lane] + pcx0[wid][lane + 32])
                         : (pcx1[wid][lane - 32] + pcx1[wid][lane]);
  int nlb = (tid < TPB - 1) ? labels[token + 1] : IGN;
  bool pair = (tid < TPB - 1) && valid && (lb == nlb) && (lb > 0);
  float ctxv = pair ? cs * (1.0f / HD) : 0.f;

  unsigned long long bv = __ballot(valid);
  unsigned long long bp = __ballot(pair);
#pragma unroll
  for (int off = 32; off; off >>= 1) {
    cev  += __shfl_xor(cev, off, 64);
    ctxv += __shfl_xor(ctxv, off, 64);
  }
  if (lane == 0) { sce[wid] = cev; sctx[wid] = ctxv; svc[wid] = __popcll(bv); spc[wid] = __popcll(bp); }

  if (wid == 3) {   // cross-block boundary pair (b*256+255, b*256+256)
    int t = b * TPB + TPB - 1;
    float bc = 0.f; int bn = 0;
    if (((t + 1) & (NSEQ - 1)) != 0) {
      int l0 = labels[t], l1 = labels[t + 1];
      if (l0 != IGN && l0 == l1 && l0 > 0) {
        const float* ra = emb + (size_t)t * HD;
        const float* rbp = ra + HD;
        float a = 0.f;
#pragma unroll
        for (int j = 0; j < 6; ++j) {
          float dd = ra[lane + 64 * j] - rbp[lane + 64 * j];
          a = fmaf(dd, dd, a);
        }
#pragma unroll
        for (int off = 32; off; off >>= 1) a += __shfl_xor(a, off, 64);
        bc = a * (1.0f / HD); bn = 1;
      }
    }
    if (lane == 0) { sbctx = bc; sbcnt = bn; }
  }
  __syncthreads();
  if (tid < 16) {
    ws->blk_a[b][tid] = sla[tid];
    ws->blk_p[b][tid] = slp[tid];
    ws->blk_c[b][tid] = slc[tid];
  }
  if (tid == 16) ws->blk_d[b] = sld;
  if (tid == 0) {
    ws->ce_part[b]  = sce[0] + sce[1] + sce[2] + sce[3];
    ws->ce_cnt[b]   = svc[0] + svc[1] + svc[2] + svc[3];
    ws->ctx_part[b] = sctx[0] + sctx[1] + sctx[2] + sctx[3] + sbctx;
    ws->ctx_cnt[b]  = spc[0] + spc[1] + spc[2] + spc[3] + sbcnt;
  }
}

// ---------------- finalize (round-7 verbatim) ----------------
__global__ __launch_bounds__(256) void k_final(const float* __restrict__ emb,
                                               WS* __restrict__ ws,
                                               float* __restrict__ out) {
  __shared__ double rce[256], rctx[256];
  __shared__ int rvc[256], rpc[256], rd[256];
  __shared__ int M1[256], M2[256], CN[256];
  __shared__ int ga[16], gp[16], gc[16];
  __shared__ float qs[4]; __shared__ int qc[4];
  const int tid = threadIdx.x, lane = tid & 63, wid = tid >> 6;

  rce[tid]  = ws->ce_part[tid];
  rctx[tid] = ws->ctx_part[tid];
  rvc[tid]  = ws->ce_cnt[tid];
  rpc[tid]  = ws->ctx_cnt[tid];
  rd[tid]   = ws->blk_d[tid];

  {
    const int type = tid & 15, seg = tid >> 4;
    int m1 = BIGI, m2 = BIGI, cnt = 0;
#pragma unroll 4
    for (int k = 0; k < 16; ++k) {
      int bb = seg * 16 + k;
      int x = ws->blk_a[bb][type];
      if (x < m1) { m2 = m1; m1 = x; } else if (x < m2) { m2 = x; }
      int y = ws->blk_p[bb][type];
      if (y < m1) { m2 = m1; m1 = y; } else if (y < m2) { m2 = y; }
      cnt += ws->blk_c[bb][type];
    }
    M1[tid] = m1; M2[tid] = m2; CN[tid] = cnt;
  }
  __syncthreads();
  for (int s = 128; s > 0; s >>= 1) {
    if (tid < s) {
      rce[tid] += rce[tid + s]; rctx[tid] += rctx[tid + s];
      rvc[tid] += rvc[tid + s]; rpc[tid] += rpc[tid + s];
      rd[tid] = min(rd[tid], rd[tid + s]);
    }
    __syncthreads();
  }
  if (tid < 16) {
    int m1 = BIGI, m2 = BIGI, cnt = 0;
    for (int seg = 0; seg < 16; ++seg) {
      int a1 = M1[seg * 16 + tid], a2 = M2[seg * 16 + tid];
      int n1 = min(m1, a1);
      int n2 = min(max(m1, a1), min(m2, a2));
      m1 = n1; m2 = n2;
      cnt += CN[seg * 16 + tid];
    }
    ga[tid] = m1; gp[tid] = m2; gc[tid] = cnt;
  }
  __syncthreads();

  const int gd = rd[0];
  float qsum = 0.f; int qcnt = 0;
  for (int tt = 0; tt < 4; ++tt) {
    int t = wid * 4 + tt;
    int a = ga[t], p = gp[t], c = gc[t];
    int nmin = BIGI;
#pragma unroll
    for (int u = 0; u < 16; ++u) if (u != t) nmin = min(nmin, ga[u]);
    bool ok = (c >= 2) && (nmin < BIGI) && (gd < BIGI);
    if (ok) {
      const float* A  = emb + (size_t)min(a, NT - 1) * HD;
      const float* P  = emb + (size_t)min(p, NT - 1) * HD;
      const float* Ng = emb + (size_t)min(nmin, NT - 1) * HD;
      const float* D  = emb + (size_t)min(gd, NT - 1) * HD;
      float sap = 0.f, san = 0.f, sad = 0.f;
#pragma unroll
      for (int j = 0; j < 6; ++j) {
        int idx = lane + 64 * j;
        float av = A[idx];
        float d1 = av - P[idx] + 1e-6f;  sap = fmaf(d1, d1, sap);
        float d2 = av - Ng[idx] + 1e-6f; san = fmaf(d2, d2, san);
        float d3 = av - D[idx] + 1e-6f;  sad = fmaf(d3, d3, sad);
      }
#pragma unroll
      for (int off = 32; off; off >>= 1) {
        sap += __shfl_xor(sap, off, 64);
        san += __shfl_xor(san, off, 64);
        sad += __shfl_xor(sad, off, 64);
      }
      float pd = sqrtf(sap), nd = sqrtf(san), dd = sqrtf(sad);
      qsum += fmaxf(pd - nd + 1.0f, 0.f) + fmaxf(pd - dd + 2.0f, 0.f);
      qcnt += 1;
    }
  }
  if (lane == 0) { qs[wid] = qsum; qc[wid] = qcnt; }
  __syncthreads();
  if (tid == 0) {
    double tq = (double)qs[0] + qs[1] + qs[2] + qs[3];
    int tqc = qc[0] + qc[1] + qc[2] + qc[3];
    double ce   = rce[0] / (double)max(rvc[0], 1);
    double ctx  = (rpc[0] > 0) ? rctx[0] / (double)rpc[0] : 0.0;
    double quad = (tqc > 0) ? tq / (double)tqc : 0.0;
    out[0] = (float)(ce + 0.5 * quad + 0.1 * ctx);
  }
}

extern "C" void kernel_launch(void* const* d_in, const int* in_sizes, int n_in,
                              void* d_out, int out_size, void* d_ws, size_t ws_size,
                              hipStream_t stream) {
  const float* emb    = (const float*)d_in[0];
  const float* cw     = (const float*)d_in[1];
  const float* cb     = (const float*)d_in[2];
  const int*   labels = (const int*)d_in[3];
  const int*   mask   = (const int*)d_in[4];
  WS* ws = (WS*)d_ws;
  float* out = (float*)d_out;

  k_main <<<NBLK, TPB, 0, stream>>>(emb, cw, cb, labels, mask, ws);
  k_final<<<1, 256, 0, stream>>>(emb, ws, out);
}

// Round 10
// 37.804 us; speedup vs baseline: 1.9542x; 1.0438x over previous
//
#include <hip/hip_runtime.h>

#define NL 17
#define IGN (-100)
#define HD 384
#define NSEQ 1024
#define NT 65536
#define BIGI NT
#define TPB 256
#define NBLK (NT / TPB)        // 256
#define NCHUNK 12              // 384 / 32 cols
#define CF4 8                  // float4 per row per chunk
#define WPAD 392               // u16 row stride for bf16 W

typedef unsigned int u32;
typedef unsigned short u16;
typedef __attribute__((ext_vector_type(8))) short bf16x8;
typedef __attribute__((ext_vector_type(16))) float f32x16;

#define GLOAD_LDS16(g, l) __builtin_amdgcn_global_load_lds(                    \
    (const __attribute__((address_space(1))) u32*)(g),                         \
    (__attribute__((address_space(3))) u32*)(l), 16, 0, 0)

__device__ __forceinline__ u32 cvtpk(float lo, float hi) {
  u32 u;
  asm("v_cvt_pk_bf16_f32 %0, %1, %2" : "=v"(u) : "v"(lo), "v"(hi));
  return u;
}

struct WS {
  float ce_part[NBLK];
  float ctx_part[NBLK];
  int   ce_cnt[NBLK];
  int   ctx_cnt[NBLK];
  int   blk_a[NBLK][16];
  int   blk_p[NBLK][16];
  int   blk_c[NBLK][16];
  int   blk_d[NBLK];
};

// ------- main: per-wave private tiles, ZERO barriers in stream loop -------
__global__ __launch_bounds__(256, 1) void k_main(const float* __restrict__ emb,
                                                 const float* __restrict__ cw,
                                                 const float* __restrict__ cb,
                                                 const int* __restrict__ labels,
                                                 const int* __restrict__ mask,
                                                 WS* __restrict__ ws) {
  __shared__ float4 tile[4][4][512];   // [buf][wave][64 rows x 8 f4] = 128 KB
  __shared__ u16    sWh[NL * WPAD];    // 13.3 KB W in bf16
  __shared__ float  sce[4], sctx[4];
  __shared__ int    svc[4], spc[4];
  __shared__ int    sla[16], slp[16], slc[16], sld;

  const int tid = threadIdx.x, lane = tid & 63, wid = tid >> 6;
  const int uwid = __builtin_amdgcn_readfirstlane(wid);
  const int b = blockIdx.x;
  const int token = b * TPB + tid;

  // ---- W -> LDS as bf16 (once); scan init ----
  for (int i = tid; i < NL * (HD / 2); i += TPB) {
    int c = i / (HD / 2), p = i % (HD / 2);
    u32 pk = cvtpk(cw[c * HD + 2 * p], cw[c * HD + 2 * p + 1]);
    *(u32*)&sWh[c * WPAD + 2 * p] = pk;
  }
  if (tid < 16) { sla[tid] = BIGI; slp[tid] = BIGI; slc[tid] = 0; }
  if (tid == 16) sld = BIGI;
  __syncthreads();   // drains all VMEM -> vmcnt counting below is exact

  // ---- per-wave staging geometry ----
  // wave w stages rows w*64..w*64+63; load k covers local rows k*8..k*8+7
  const int l3  = lane >> 3;                 // 0..7
  const int gc4 = (lane & 7) ^ l3;           // pre-swizzled source column
  const float* src0 = emb + ((size_t)b * TPB + wid * 64 + l3) * HD + gc4 * 4;

  auto issue = [&](int c) {
    const float* s = src0 + (size_t)c * 32;
#pragma unroll
    for (int k = 0; k < CF4; ++k)
      GLOAD_LDS16(s + (size_t)k * 8 * HD, &tile[c & 3][uwid][k * 64]);
  };

  issue(0); issue(1); issue(2);   // 24 outstanding per wave

  // ---- MFMA / ctx geometry (local rows) ----
  const int cls = lane & 31;
  const int kh  = lane >> 5;
  const int clsS = (cls < NL) ? cls : 0;
  const int rl0 = lane & 31;                 // B tile0 local row
  const int rl1 = 32 + (lane & 31);          // B tile1 local row
  const int cr0 = lane;                      // ctx own local row
  const int cr1 = (lane < 63) ? lane + 1 : 63;

  f32x16 d0 = {0.f}, d1 = {0.f};
  float ctxacc = 0.f;

  auto afrag = [&](int ch, int s) -> bf16x8 {
    if (cls < NL)
      return *(const bf16x8*)&sWh[clsS * WPAD + ch * 32 + s * 16 + kh * 8];
    union { u32 u[4]; bf16x8 v; } Z;
    Z.u[0] = 0; Z.u[1] = 0; Z.u[2] = 0; Z.u[3] = 0;
    return Z.v;
  };
  auto bfrag = [&](const float4* tb, int row, int s) -> bf16x8 {
    int g0 = (s * 4 + kh * 2) ^ (row & 7);
    int g1 = (s * 4 + kh * 2 + 1) ^ (row & 7);
    float4 f0 = tb[(row << 3) | g0];
    float4 f1 = tb[(row << 3) | g1];
    union { u32 u[4]; bf16x8 v; } X;
    X.u[0] = cvtpk(f0.x, f0.y); X.u[1] = cvtpk(f0.z, f0.w);
    X.u[2] = cvtpk(f1.x, f1.y); X.u[3] = cvtpk(f1.z, f1.w);
    return X.v;
  };

  auto compute = [&](int ch) {
    const float4* tb = (const float4*)&tile[ch & 3][wid][0];
#pragma unroll
    for (int q = 0; q < CF4; ++q) {
      float4 a  = tb[(cr0 << 3) | (q ^ (cr0 & 7))];
      float4 nb = tb[(cr1 << 3) | (q ^ (cr1 & 7))];
      float e0 = a.x - nb.x, e1 = a.y - nb.y, e2 = a.z - nb.z, e3 = a.w - nb.w;
      ctxacc = fmaf(e0, e0, fmaf(e1, e1, fmaf(e2, e2, fmaf(e3, e3, ctxacc))));
    }
    bf16x8 a0 = afrag(ch, 0), a1 = afrag(ch, 1);
    bf16x8 b00 = bfrag(tb, rl0, 0), b01 = bfrag(tb, rl0, 1);
    bf16x8 b10 = bfrag(tb, rl1, 0), b11 = bfrag(tb, rl1, 1);
    d0 = __builtin_amdgcn_mfma_f32_32x32x16_bf16(a0, b00, d0, 0, 0, 0);
    d0 = __builtin_amdgcn_mfma_f32_32x32x16_bf16(a1, b01, d0, 0, 0, 0);
    d1 = __builtin_amdgcn_mfma_f32_32x32x16_bf16(a0, b10, d1, 0, 0, 0);
    d1 = __builtin_amdgcn_mfma_f32_32x32x16_bf16(a1, b11, d1, 0, 0, 0);
  };

  // stream loop: NO barriers — per-wave self-timed with counted vmcnt
#pragma unroll 1
  for (int ch = 0; ch <= NCHUNK - 4; ++ch) {
    issue(ch + 3);   // writes buf (ch-1)&3: this wave finished reading it
    asm volatile("s_waitcnt vmcnt(24)" ::: "memory");   // chunk ch landed
    __builtin_amdgcn_sched_barrier(0);
    compute(ch);
  }
  asm volatile("s_waitcnt vmcnt(16)" ::: "memory");
  __builtin_amdgcn_sched_barrier(0);
  compute(NCHUNK - 3);
  asm volatile("s_waitcnt vmcnt(8)" ::: "memory");
  __builtin_amdgcn_sched_barrier(0);
  compute(NCHUNK - 2);
  asm volatile("s_waitcnt vmcnt(0)" ::: "memory");
  __builtin_amdgcn_sched_barrier(0);
  compute(NCHUNK - 1);

  __syncthreads();   // all waves done with private tiles -> reuse LDS

  // ---- logits [256][21] over tile[0] ----
  float* logit = (float*)&tile[0][0][0];
#pragma unroll
  for (int r = 0; r < 16; ++r) {
    int row = (r & 3) + 8 * (r >> 2) + 4 * kh;   // class
    if (row < NL) {
      logit[(wid * 64 + (lane & 31)) * 21 + row] = d0[r];
      logit[(wid * 64 + 32 + (lane & 31)) * 21 + row] = d1[r];
    }
  }
  __syncthreads();

  // ---- fused label scan ----
  int lb = labels[token];
  int mk = mask[token];
  int lbm = (mk > 0) ? lb : IGN;
  if (lbm == 0) atomicMin(&sld, token);
  else if (lbm >= 1 && lbm < NL) { atomicMin(&sla[lbm - 1], token); atomicAdd(&slc[lbm - 1], 1); }
  __syncthreads();
  if (lbm >= 1 && lbm < NL && token > sla[lbm - 1]) atomicMin(&slp[lbm - 1], token);

  // ---- softmax + CE + ctx pair ----
  float lg[NL];
#pragma unroll
  for (int c = 0; c < NL; ++c) lg[c] = logit[tid * 21 + c] + cb[c];
  float m = lg[0];
#pragma unroll
  for (int c = 1; c < NL; ++c) m = fmaxf(m, lg[c]);
  float s = 0.f;
#pragma unroll
  for (int c = 0; c < NL; ++c) s += __expf(lg[c] - m);
  float lse = m + __logf(s);
  int safe = (lb == IGN) ? 0 : lb;
  float ll = 0.f;
#pragma unroll
  for (int c = 0; c < NL; ++c) ll = (c == safe) ? lg[c] : ll;
  bool valid = (lb != IGN);
  float cev = valid ? (lse - ll) : 0.f;

  int nlb = (lane < 63) ? labels[token + 1] : IGN;
  bool pair = (lane < 63) && valid && (lb == nlb) && (lb > 0);
  float ctxv = pair ? ctxacc * (1.0f / HD) : 0.f;

  unsigned long long bv = __ballot(valid);
  unsigned long long bp = __ballot(pair);
#pragma unroll
  for (int off = 32; off; off >>= 1) {
    cev  += __shfl_xor(cev, off, 64);
    ctxv += __shfl_xor(ctxv, off, 64);
  }

  // ---- per-wave boundary pair (token w*64+63 , +1) via global reads ----
  float bc = 0.f; int bn = 0;
  {
    int t = b * TPB + wid * 64 + 63;
    if (((t + 1) & (NSEQ - 1)) != 0) {
      int l0 = labels[t], l1 = labels[t + 1];
      if (l0 != IGN && l0 == l1 && l0 > 0) {
        const float* ra = emb + (size_t)t * HD;
        const float* rbp = ra + HD;
        float a = 0.f;
#pragma unroll
        for (int j = 0; j < 6; ++j) {
          float dd = ra[lane + 64 * j] - rbp[lane + 64 * j];
          a = fmaf(dd, dd, a);
        }
#pragma unroll
        for (int off = 32; off; off >>= 1) a += __shfl_xor(a, off, 64);
        bc = a * (1.0f / HD); bn = 1;
      }
    }
  }
  if (lane == 0) {
    sce[wid]  = cev;
    sctx[wid] = ctxv + bc;
    svc[wid]  = __popcll(bv);
    spc[wid]  = __popcll(bp) + bn;
  }
  __syncthreads();
  if (tid < 16) {
    ws->blk_a[b][tid] = sla[tid];
    ws->blk_p[b][tid] = slp[tid];
    ws->blk_c[b][tid] = slc[tid];
  }
  if (tid == 16) ws->blk_d[b] = sld;
  if (tid == 0) {
    ws->ce_part[b]  = sce[0] + sce[1] + sce[2] + sce[3];
    ws->ce_cnt[b]   = svc[0] + svc[1] + svc[2] + svc[3];
    ws->ctx_part[b] = sctx[0] + sctx[1] + sctx[2] + sctx[3];
    ws->ctx_cnt[b]  = spc[0] + spc[1] + spc[2] + spc[3];
  }
}

// ---------------- finalize (round-7 verbatim) ----------------
__global__ __launch_bounds__(256) void k_final(const float* __restrict__ emb,
                                               WS* __restrict__ ws,
                                               float* __restrict__ out) {
  __shared__ double rce[256], rctx[256];
  __shared__ int rvc[256], rpc[256], rd[256];
  __shared__ int M1[256], M2[256], CN[256];
  __shared__ int ga[16], gp[16], gc[16];
  __shared__ float qs[4]; __shared__ int qc[4];
  const int tid = threadIdx.x, lane = tid & 63, wid = tid >> 6;

  rce[tid]  = ws->ce_part[tid];
  rctx[tid] = ws->ctx_part[tid];
  rvc[tid]  = ws->ce_cnt[tid];
  rpc[tid]  = ws->ctx_cnt[tid];
  rd[tid]   = ws->blk_d[tid];

  {
    const int type = tid & 15, seg = tid >> 4;
    int m1 = BIGI, m2 = BIGI, cnt = 0;
#pragma unroll 4
    for (int k = 0; k < 16; ++k) {
      int bb = seg * 16 + k;
      int x = ws->blk_a[bb][type];
      if (x < m1) { m2 = m1; m1 = x; } else if (x < m2) { m2 = x; }
      int y = ws->blk_p[bb][type];
      if (y < m1) { m2 = m1; m1 = y; } else if (y < m2) { m2 = y; }
      cnt += ws->blk_c[bb][type];
    }
    M1[tid] = m1; M2[tid] = m2; CN[tid] = cnt;
  }
  __syncthreads();
  for (int s = 128; s > 0; s >>= 1) {
    if (tid < s) {
      rce[tid] += rce[tid + s]; rctx[tid] += rctx[tid + s];
      rvc[tid] += rvc[tid + s]; rpc[tid] += rpc[tid + s];
      rd[tid] = min(rd[tid], rd[tid + s]);
    }
    __syncthreads();
  }
  if (tid < 16) {
    int m1 = BIGI, m2 = BIGI, cnt = 0;
    for (int seg = 0; seg < 16; ++seg) {
      int a1 = M1[seg * 16 + tid], a2 = M2[seg * 16 + tid];
      int n1 = min(m1, a1);
      int n2 = min(max(m1, a1), min(m2, a2));
      m1 = n1; m2 = n2;
      cnt += CN[seg * 16 + tid];
    }
    ga[tid] = m1; gp[tid] = m2; gc[tid] = cnt;
  }
  __syncthreads();

  const int gd = rd[0];
  float qsum = 0.f; int qcnt = 0;
  for (int tt = 0; tt < 4; ++tt) {
    int t = wid * 4 + tt;
    int a = ga[t], p = gp[t], c = gc[t];
    int nmin = BIGI;
#pragma unroll
    for (int u = 0; u < 16; ++u) if (u != t) nmin = min(nmin, ga[u]);
    bool ok = (c >= 2) && (nmin < BIGI) && (gd < BIGI);
    if (ok) {
      const float* A  = emb + (size_t)min(a, NT - 1) * HD;
      const float* P  = emb + (size_t)min(p, NT - 1) * HD;
      const float* Ng = emb + (size_t)min(nmin, NT - 1) * HD;
      const float* D  = emb + (size_t)min(gd, NT - 1) * HD;
      float sap = 0.f, san = 0.f, sad = 0.f;
#pragma unroll
      for (int j = 0; j < 6; ++j) {
        int idx = lane + 64 * j;
        float av = A[idx];
        float d1 = av - P[idx] + 1e-6f;  sap = fmaf(d1, d1, sap);
        float d2 = av - Ng[idx] + 1e-6f; san = fmaf(d2, d2, san);
        float d3 = av - D[idx] + 1e-6f;  sad = fmaf(d3, d3, sad);
      }
#pragma unroll
      for (int off = 32; off; off >>= 1) {
        sap += __shfl_xor(sap, off, 64);
        san += __shfl_xor(san, off, 64);
        sad += __shfl_xor(sad, off, 64);
      }
      float pd = sqrtf(sap), nd = sqrtf(san), dd = sqrtf(sad);
      qsum += fmaxf(pd - nd + 1.0f, 0.f) + fmaxf(pd - dd + 2.0f, 0.f);
      qcnt += 1;
    }
  }
  if (lane == 0) { qs[wid] = qsum; qc[wid] = qcnt; }
  __syncthreads();
  if (tid == 0) {
    double tq = (double)qs[0] + qs[1] + qs[2] + qs[3];
    int tqc = qc[0] + qc[1] + qc[2] + qc[3];
    double ce   = rce[0] / (double)max(rvc[0], 1);
    double ctx  = (rpc[0] > 0) ? rctx[0] / (double)rpc[0] : 0.0;
    double quad = (tqc > 0) ? tq / (double)tqc : 0.0;
    out[0] = (float)(ce + 0.5 * quad + 0.1 * ctx);
  }
}

extern "C" void kernel_launch(void* const* d_in, const int* in_sizes, int n_in,
                              void* d_out, int out_size, void* d_ws, size_t ws_size,
                              hipStream_t stream) {
  const float* emb    = (const float*)d_in[0];
  const float* cw     = (const float*)d_in[1];
  const float* cb     = (const float*)d_in[2];
  const int*   labels = (const int*)d_in[3];
  const int*   mask   = (const int*)d_in[4];
  WS* ws = (WS*)d_ws;
  float* out = (float*)d_out;

  k_main <<<NBLK, TPB, 0, stream>>>(emb, cw, cb, labels, mask, ws);
  k_final<<<1, 256, 0, stream>>>(emb, ws, out);
}